// Round 18
// baseline (1923.604 us; speedup 1.0000x reference)
//
#include <hip/hip_runtime.h>
#include <hip/hip_bf16.h>
#include <math.h>

#define TLEN 1022
#define SLEN 1024
#define NB   64
#define NE   256
#define NF   256
#define NH   256
#define NG   1024
#define TC   128      // chunk length (8 chunks: 7x128 + 126); 2 xh buffers

typedef _Float16 h2_t __attribute__((ext_vector_type(2)));
typedef __attribute__((ext_vector_type(8))) short bf16x8;
typedef __attribute__((ext_vector_type(4))) float f32x4;

#if defined(__has_builtin)
# if __has_builtin(__builtin_amdgcn_sdot4)
#  define HAVE_SDOT4 1
# endif
#endif
#ifndef HAVE_SDOT4
# define HAVE_SDOT4 0
#endif

__device__ __forceinline__ float sigm(float x){ return 1.f/(1.f+__expf(-x)); }
__device__ __forceinline__ float tanh_(float x){ return 1.f - 2.f/(__expf(2.f*x)+1.f); }

__device__ __forceinline__ int sdot4_acc(unsigned int a, unsigned int b, int acc){
#if HAVE_SDOT4
  return __builtin_amdgcn_sdot4((int)a, (int)b, acc, false);
#else
  int s = acc;
  #pragma unroll
  for (int e=0;e<4;++e){
    int av = (int)(signed char)((a >> (8*e)) & 0xff);
    int bv = (int)(signed char)((b >> (8*e)) & 0xff);
    s += av*bv;
  }
  return s;
#endif
}
__device__ __forceinline__ unsigned short f2bf(float x){
  __hip_bfloat16 b = __float2bfloat16(x);
  return __builtin_bit_cast(unsigned short, b);
}

// bias4[g] = b_ih[g] + b_hh[g] + sum_f conv_b[f]*w_ih[g][f]
__global__ __launch_bounds__(256) void k_bias(const float* __restrict__ conv_b,
                                              const float* __restrict__ w_ih,
                                              const float* __restrict__ b_ih,
                                              const float* __restrict__ b_hh,
                                              float* __restrict__ bias4){
  int g = blockIdx.x*256 + threadIdx.x;
  const float* row = w_ih + (size_t)g*NF;
  float s = b_ih[g] + b_hh[g];
  for (int f=0; f<NF; f+=4){
    float4 w4 = *(const float4*)(row+f);
    float4 c4 = *(const float4*)(conv_b+f);
    s += w4.x*c4.x + w4.y*c4.y + w4.z*c4.z + w4.w*c4.w;
  }
  bias4[g] = s;
}

// per-row quantization scales for w_hh
__global__ __launch_bounds__(256) void k_scale(const float* __restrict__ w_hh,
                                               float* __restrict__ stepv,
                                               float* __restrict__ sws){
  int row = blockIdx.x*256 + threadIdx.x;
  const float* p = w_hh + (size_t)row*NH;
  float m = 0.f;
  for (int c=0;c<NH;c+=4){
    float4 v = *(const float4*)(p+c);
    m = fmaxf(m, fmaxf(fmaxf(fabsf(v.x),fabsf(v.y)), fmaxf(fabsf(v.z),fabsf(v.w))));
  }
  float st = fmaxf(m, 1e-20f) / 127.f;
  stepv[row] = st;
  sws[row]   = st / 127.f;
}

// Pack w_hh -> i8 (1024-thread rnn layout). pq6[i][tid], i<16:
// tid=(w*64+l), kq=w>>2, jq=w&3. Comp r: row=jq*256+l*4+r, cols kq*64+i*4+e.
__global__ __launch_bounds__(256) void k_pack6(const float* __restrict__ w_hh,
                                               const float* __restrict__ stepv,
                                               uint4* __restrict__ pq6){
  int gid = blockIdx.x*256 + threadIdx.x;   // 0..16383
  int i = gid >> 10, tid = gid & 1023;
  int w = tid >> 6, l = tid & 63, kq = w >> 2, jq = w & 3;
  unsigned int words[4];
  #pragma unroll
  for (int r=0; r<4; ++r){
    int row = jq*256 + l*4 + r;
    float st = stepv[row];
    unsigned int acc = 0;
    #pragma unroll
    for (int e=0; e<4; ++e){
      int col = kq*64 + i*4 + e;
      int q = __float2int_rn(w_hh[(size_t)row*NH + col] / st);
      q = max(-127, min(127, q));
      acc |= ((unsigned int)(unsigned char)(signed char)q) << (8*e);
    }
    words[r] = acc;
  }
  pq6[(size_t)i*1024 + tid] = make_uint4(words[0],words[1],words[2],words[3]);
}

// CW2T[g][k] = sum_f w_ih[g][f] * conv_w_flat[k][f]   (bf16 [1024][768])
__global__ __launch_bounds__(256) void k_cw2(const float* __restrict__ w_ih,
                                             const float* __restrict__ conv_w,
                                             unsigned short* __restrict__ cw2t){
  __shared__ float al[64][17];
  __shared__ float bl[16][64];
  const int n0  = blockIdx.x*64;
  const int m0  = blockIdx.y*64;
  const int tid = threadIdx.x;
  const int ty  = tid>>4, tx = tid&15;
  const int rr  = tid>>2, kq = (tid&3)<<2;
  float acc[4][4];
  #pragma unroll
  for (int i=0;i<4;++i){ acc[i][0]=0.f; acc[i][1]=0.f; acc[i][2]=0.f; acc[i][3]=0.f; }

  for (int k0=0; k0<256; k0+=16){
    __syncthreads();
    {
      float4 v = *(const float4*)(w_ih + (size_t)(m0+rr)*NF + k0 + kq);
      al[rr][kq+0]=v.x; al[rr][kq+1]=v.y; al[rr][kq+2]=v.z; al[rr][kq+3]=v.w;
      float4 u = *(const float4*)(conv_w + (size_t)(n0+rr)*NF + k0 + kq);
      bl[kq+0][rr]=u.x; bl[kq+1][rr]=u.y; bl[kq+2][rr]=u.z; bl[kq+3][rr]=u.w;
    }
    __syncthreads();
    #pragma unroll
    for (int kk=0; kk<16; ++kk){
      float a0=al[ty*4+0][kk], a1=al[ty*4+1][kk], a2=al[ty*4+2][kk], a3=al[ty*4+3][kk];
      float4 bv = *(const float4*)&bl[kk][tx*4];
      acc[0][0]+=a0*bv.x; acc[0][1]+=a0*bv.y; acc[0][2]+=a0*bv.z; acc[0][3]+=a0*bv.w;
      acc[1][0]+=a1*bv.x; acc[1][1]+=a1*bv.y; acc[1][2]+=a1*bv.z; acc[1][3]+=a1*bv.w;
      acc[2][0]+=a2*bv.x; acc[2][1]+=a2*bv.y; acc[2][2]+=a2*bv.z; acc[2][3]+=a2*bv.w;
      acc[3][0]+=a3*bv.x; acc[3][1]+=a3*bv.y; acc[3][2]+=a3*bv.z; acc[3][3]+=a3*bv.w;
    }
  }
  #pragma unroll
  for (int i=0;i<4;++i){
    size_t r = (size_t)m0 + ty*4 + i;
    unsigned int p0 = (unsigned int)f2bf(acc[i][0]) | ((unsigned int)f2bf(acc[i][1])<<16);
    unsigned int p1 = (unsigned int)f2bf(acc[i][2]) | ((unsigned int)f2bf(acc[i][3])<<16);
    *(uint2*)(cw2t + r*768 + n0 + tx*4) = make_uint2(p0, p1);
  }
}

// Fused chunk kernel. WGs [0,32) run the RNN for chunk c, TWO batches per WG
// (weight reads, barriers, tail amortize 2x); WGs [32, 32+n_fxg) produce chunk
// c+1's xh on otherwise-idle CUs. 1024 thr/WG.
__global__ __attribute__((amdgpu_flat_work_group_size(1024,1024)))
__attribute__((amdgpu_waves_per_eu(4,4)))
void k_step(const int* __restrict__ ipts, const float* __restrict__ emb,
            const unsigned short* __restrict__ cw2t, const float* __restrict__ bias4,
            const unsigned short* __restrict__ xh_r, unsigned short* __restrict__ xh_w,
            const uint4* __restrict__ pq6, const float* __restrict__ sws,
            const float* __restrict__ h0, const float* __restrict__ c0,
            const int* __restrict__ seqlen,
            const float* __restrict__ lin_w, const float* __restrict__ lin_b,
            float* __restrict__ h_ws, float* __restrict__ c_ws, float* __restrict__ ms_ws,
            float* __restrict__ out,
            int t0r, int tcount, int is_first, int is_last,
            int t0f, int do_rnn, int n_fxg){
  __shared__ __align__(16) char smem[133632];
  const int tid  = threadIdx.x;
  const int nrnn = do_rnn ? 32 : 0;

  if ((int)blockIdx.x < nrnn){
    // ================= RNN path: 2 batches per WG =================
    uint4*        wlds = (uint4*)smem;                        // [6*1024] 96 KB
    float*        part = (float*)(smem + 98304);              // [2][4][1024] 32 KB
    unsigned int* hq   = (unsigned int*)(smem + 131072);      // [2][64]
    float*        red  = (float*)(smem + 131584);             // [2][256]
    const int b0 = blockIdx.x * 2;
    const int l  = tid & 63, w = tid >> 6;
    const int kq = w >> 2, jq = w & 3;
    const int rbase = jq*256 + l*4;
    const int bsel  = tid >> 8;            // valid when tid<512
    const int uu    = tid & 255;

    #pragma unroll
    for (int i=0;i<6;++i) wlds[i*1024 + tid] = pq6[(size_t)i*1024 + tid];

    uint4 wreg[10];
    #pragma unroll
    for (int i=6;i<16;++i) wreg[i-6] = pq6[(size_t)i*1024 + tid];
    #pragma unroll
    for (int i=0;i<10;++i)
      asm volatile("" : "+v"(wreg[i].x), "+v"(wreg[i].y), "+v"(wreg[i].z), "+v"(wreg[i].w));

    float swr[4];
    #pragma unroll
    for (int r=0;r<4;++r) swr[r] = sws[rbase + r];

    int L = 0;
    float creg = 0.f, msum = 0.f, hlast = 0.f;
    if (tid < 512){
      const int b = b0 + bsel;
      L = seqlen[b];
      float hv;
      if (is_first){ hv = h0[(size_t)b*NH + uu]; creg = c0[(size_t)b*NH + uu]; }
      else { hv = h_ws[b*256 + uu]; creg = c_ws[b*256 + uu]; msum = ms_ws[b*256 + uu]; }
      hlast = hv;
      int q = __float2int_rn(hv * 127.f); q = max(-127, min(127, q));
      ((signed char*)hq)[bsel*256 + uu] = (signed char)q;
    }
    __syncthreads();

    const unsigned short* xrow = xh_r + (size_t)(b0 + bsel)*NG + uu;

    for (int tl=0; tl<tcount; ++tl){
      // prefetch xg for this thread's (batch, unit): 4 raw f16
      unsigned short xr0=0, xr1=0, xr2=0, xr3=0;
      if (tid < 512){
        const unsigned short* xr = xrow + (size_t)tl*NB*NG;
        xr0 = xr[0]; xr1 = xr[256]; xr2 = xr[512]; xr3 = xr[768];
      }

      // h slices for both batches (broadcast b128 reads)
      unsigned int h0w[16], h1w[16];
      #pragma unroll
      for (int c=0;c<4;++c){
        uint4 t0_ = *(const uint4*)&hq[0*64 + kq*16 + c*4];
        uint4 t1_ = *(const uint4*)&hq[1*64 + kq*16 + c*4];
        h0w[c*4+0]=t0_.x; h0w[c*4+1]=t0_.y; h0w[c*4+2]=t0_.z; h0w[c*4+3]=t0_.w;
        h1w[c*4+0]=t1_.x; h1w[c*4+1]=t1_.y; h1w[c*4+2]=t1_.z; h1w[c*4+3]=t1_.w;
      }

      int pa0[4] = {0,0,0,0}, pa1[4] = {0,0,0,0};
      #pragma unroll
      for (int i=0;i<16;++i){
        uint4 wv4 = (i < 6) ? wlds[i*1024 + tid] : wreg[i-6];
        unsigned int a0 = h0w[i], a1 = h1w[i];
        pa0[0] = sdot4_acc(wv4.x, a0, pa0[0]);  pa1[0] = sdot4_acc(wv4.x, a1, pa1[0]);
        pa0[1] = sdot4_acc(wv4.y, a0, pa0[1]);  pa1[1] = sdot4_acc(wv4.y, a1, pa1[1]);
        pa0[2] = sdot4_acc(wv4.z, a0, pa0[2]);  pa1[2] = sdot4_acc(wv4.z, a1, pa1[2]);
        pa0[3] = sdot4_acc(wv4.w, a0, pa0[3]);  pa1[3] = sdot4_acc(wv4.w, a1, pa1[3]);
      }
      *(float4*)&part[0*4096 + kq*1024 + rbase] = make_float4(
          (float)pa0[0]*swr[0], (float)pa0[1]*swr[1],
          (float)pa0[2]*swr[2], (float)pa0[3]*swr[3]);
      *(float4*)&part[1*4096 + kq*1024 + rbase] = make_float4(
          (float)pa1[0]*swr[0], (float)pa1[1]*swr[1],
          (float)pa1[2]*swr[2], (float)pa1[3]*swr[3]);
      __syncthreads();

      if (tid < 512){
        unsigned short xr4[4] = {xr0, xr1, xr2, xr3};
        const float* pb = part + bsel*4096;
        float a[4];
        #pragma unroll
        for (int g=0; g<4; ++g){
          float s = (float)__builtin_bit_cast(_Float16, xr4[g]);
          int idx = g*256 + uu;
          #pragma unroll
          for (int k=0;k<4;++k) s += pb[k*1024 + idx];
          a[g] = s;
        }
        float si = sigm(a[0]), sf = sigm(a[1]), so = sigm(a[3]);
        float tg = tanh_(a[2]);
        creg = sf*creg + si*tg;
        float h2 = so*tanh_(creg);
        if (t0r + tl < L) msum += h2;
        hlast = h2;
        int q2 = __float2int_rn(h2 * 127.f); q2 = max(-127, min(127, q2));
        ((signed char*)hq)[bsel*256 + uu] = (signed char)q2;
      }
      __syncthreads();
    }

    if (tid < 512){
      const int b = b0 + bsel;
      h_ws[b*256 + uu]  = hlast;
      c_ws[b*256 + uu]  = creg;
      ms_ws[b*256 + uu] = msum;
    }

    if (is_last){
      if (tid < 512) red[bsel*256 + uu] = (msum / (float)L) * lin_w[uu];
      __syncthreads();
      if (tid < 128){
        int bs = tid >> 6, ln = tid & 63;
        float s = red[bs*256 + ln] + red[bs*256 + ln + 64]
                + red[bs*256 + ln + 128] + red[bs*256 + ln + 192];
        #pragma unroll
        for (int off=32; off>0; off>>=1) s += __shfl_down(s, off);
        if (ln==0) out[b0 + bs] = sigm(s + lin_b[0]);
      }
    }
  } else {
    // ================= fxg path (produces next chunk's xh) =================
    int fidx = (int)blockIdx.x - nrnn;
    if (fidx >= n_fxg) return;
    unsigned short* A_l  = (unsigned short*)smem;             // [128*72]
    unsigned short* B_l  = (unsigned short*)(smem + 18432);   // [256*72]
    int*            tokl = (int*)(smem + 55296);              // [4*64]
    const int l  = tid & 63, wv = tid >> 6;
    const int m0 = (fidx >> 2) * 128;
    const int n0 = (fidx & 3) * 256;
    const int TL0 = m0 >> 6;

    if (tid < 256){
      int tv = tid >> 6, bb = tid & 63;
      int s = t0f + TL0 + tv;
      tokl[tid] = (s < SLEN) ? ipts[bb*SLEN + s] : 0;
    }

    f32x4 acc[2][4];
    #pragma unroll
    for (int mt=0; mt<2; ++mt)
      #pragma unroll
      for (int nt=0; nt<4; ++nt)
        acc[mt][nt] = (f32x4){0.f,0.f,0.f,0.f};

    const int wm = wv >> 2, wn = wv & 3;
    const int lr = l & 15, lk = l >> 4;

    for (int ks = 0; ks < 12; ++ks){
      const int w0 = ks >> 2;
      const int e0 = (ks & 3) << 6;
      __syncthreads();
      {
        int row = tid >> 3, off = tid & 7;
        int tok = tokl[((row>>6) + w0)*64 + (row & 63)];
        const float* src = emb + (size_t)tok*NE + e0 + off*8;
        float4 f0 = *(const float4*)src;
        float4 f1 = *(const float4*)(src+4);
        unsigned int p0 = (unsigned int)f2bf(f0.x) | ((unsigned int)f2bf(f0.y)<<16);
        unsigned int p1 = (unsigned int)f2bf(f0.z) | ((unsigned int)f2bf(f0.w)<<16);
        unsigned int p2 = (unsigned int)f2bf(f1.x) | ((unsigned int)f2bf(f1.y)<<16);
        unsigned int p3 = (unsigned int)f2bf(f1.z) | ((unsigned int)f2bf(f1.w)<<16);
        *(uint4*)&A_l[row*72 + off*8] = make_uint4(p0,p1,p2,p3);
      }
      #pragma unroll
      for (int s2 = 0; s2 < 2; ++s2){
        int seg = tid + s2*1024;
        int row = seg >> 3, off = seg & 7;
        uint4 v = *(const uint4*)(cw2t + (size_t)(n0+row)*768 + (ks<<6) + off*8);
        *(uint4*)&B_l[row*72 + off*8] = v;
      }
      __syncthreads();
      #pragma unroll
      for (int kf = 0; kf < 2; ++kf){
        bf16x8 af[2], bfr[4];
        #pragma unroll
        for (int mt=0; mt<2; ++mt)
          af[mt] = *(const bf16x8*)&A_l[(wm*32 + mt*16 + lr)*72 + kf*32 + lk*8];
        #pragma unroll
        for (int nt=0; nt<4; ++nt)
          bfr[nt] = *(const bf16x8*)&B_l[(wn*64 + nt*16 + lr)*72 + kf*32 + lk*8];
        #pragma unroll
        for (int mt=0; mt<2; ++mt)
          #pragma unroll
          for (int nt=0; nt<4; ++nt)
            acc[mt][nt] = __builtin_amdgcn_mfma_f32_16x16x32_bf16(af[mt], bfr[nt], acc[mt][nt], 0,0,0);
      }
    }

    float bia[4];
    #pragma unroll
    for (int nt=0; nt<4; ++nt) bia[nt] = bias4[n0 + wn*64 + nt*16 + lr];
    #pragma unroll
    for (int mt=0; mt<2; ++mt){
      #pragma unroll
      for (int nt=0; nt<4; ++nt){
        #pragma unroll
        for (int r=0; r<4; ++r){
          int row = m0 + wm*32 + mt*16 + lk*4 + r;
          int col = n0 + wn*64 + nt*16 + lr;
          _Float16 hv = (_Float16)(acc[mt][nt][r] + bia[nt]);
          xh_w[(size_t)row*NG + col] = __builtin_bit_cast(unsigned short, hv);
        }
      }
    }
  }
}

extern "C" void kernel_launch(void* const* d_in, const int* in_sizes, int n_in,
                              void* d_out, int out_size, void* d_ws, size_t ws_size,
                              hipStream_t stream){
  const int*   ipts   = (const int*)d_in[0];
  const int*   seqlen = (const int*)d_in[1];
  const float* h0     = (const float*)d_in[2];
  const float* c0     = (const float*)d_in[3];
  const float* emb    = (const float*)d_in[4];
  const float* conv_w = (const float*)d_in[5];
  const float* conv_b = (const float*)d_in[6];
  const float* w_ih   = (const float*)d_in[7];
  const float* w_hh   = (const float*)d_in[8];
  const float* b_ih   = (const float*)d_in[9];
  const float* b_hh   = (const float*)d_in[10];
  const float* lin_w  = (const float*)d_in[11];
  const float* lin_b  = (const float*)d_in[12];
  float* out = (float*)d_out;

  char* ws = (char*)d_ws;
  const size_t XH_B   = (size_t)TC*NB*NG*2;       // 16.78 MB each
  const size_t CW2_B  = (size_t)NG*768*2;         // 1.57 MB
  const size_t PQ_B   = (size_t)16*1024*16;       // 256 KB
  size_t off = 0;
  unsigned short* xhA   = (unsigned short*)(ws + off); off += XH_B;
  unsigned short* xhB   = (unsigned short*)(ws + off); off += XH_B;
  unsigned short* cw2t  = (unsigned short*)(ws + off); off += CW2_B;
  uint4*          pq6   = (uint4*)(ws + off);          off += PQ_B;
  float*          stepv = (float*)(ws + off);          off += 4096;
  float*          sws   = (float*)(ws + off);          off += 4096;
  float*          bias4 = (float*)(ws + off);          off += 4096;
  float*          h_ws  = (float*)(ws + off);          off += 65536;
  float*          c_ws  = (float*)(ws + off);          off += 65536;
  float*          ms_ws = (float*)(ws + off);          off += 65536;

  k_bias <<<dim3(4),      dim3(256), 0, stream>>>(conv_b, w_ih, b_ih, b_hh, bias4);
  k_scale<<<dim3(4),      dim3(256), 0, stream>>>(w_hh, stepv, sws);
  k_pack6<<<dim3(64),     dim3(256), 0, stream>>>(w_hh, stepv, pq6);
  k_cw2  <<<dim3(12, 16), dim3(256), 0, stream>>>(w_ih, conv_w, cw2t);

  unsigned short* bufs[2] = {xhA, xhB};
  const int nchunks = (TLEN + TC - 1) / TC;   // 8
  auto nf_of = [](int tc){ return 4 * ((tc + 1) / 2); };

  // boot: produce chunk 0's xh (fxg-only launch)
  {
    int tc0 = (TLEN < TC) ? TLEN : TC;
    int nf0 = nf_of(tc0);
    k_step<<<dim3(nf0), dim3(1024), 0, stream>>>(
        ipts, emb, cw2t, bias4, bufs[0], bufs[0], pq6, sws, h0, c0, seqlen,
        lin_w, lin_b, h_ws, c_ws, ms_ws, out,
        0, 0, 0, 0, /*t0f=*/0, /*do_rnn=*/0, nf0);
  }

  for (int c = 0; c < nchunks; ++c){
    int t0 = c*TC;
    int tcount = (TLEN - t0 < TC) ? (TLEN - t0) : TC;
    int nf = 0, t0f = 0;
    unsigned short* xw = bufs[0];
    if (c + 1 < nchunks){
      int t0n = (c+1)*TC;
      int tcn = (TLEN - t0n < TC) ? (TLEN - t0n) : TC;
      nf  = nf_of(tcn);
      t0f = t0n;
      xw  = bufs[(c+1) & 1];
    }
    k_step<<<dim3(32 + nf), dim3(1024), 0, stream>>>(
        ipts, emb, cw2t, bias4, bufs[c & 1], xw, pq6, sws, h0, c0, seqlen,
        lin_w, lin_b, h_ws, c_ws, ms_ws, out,
        t0, tcount, (c==0), (c==nchunks-1), t0f, /*do_rnn=*/1, nf);
  }
}

// Round 19
// 1204.026 us; speedup vs baseline: 1.5976x; 1.5976x over previous
//
#include <hip/hip_runtime.h>
#include <hip/hip_bf16.h>
#include <math.h>

#define TLEN 1022
#define SLEN 1024
#define NB   64
#define NE   256
#define NF   256
#define NH   256
#define NG   1024
#define TC   128      // chunk length (8 chunks: 7x128 + 126); 2 xh buffers

typedef _Float16 h2_t __attribute__((ext_vector_type(2)));
typedef __attribute__((ext_vector_type(8))) short bf16x8;
typedef __attribute__((ext_vector_type(4))) float f32x4;

#if defined(__has_builtin)
# if __has_builtin(__builtin_amdgcn_sdot4)
#  define HAVE_SDOT4 1
# endif
#endif
#ifndef HAVE_SDOT4
# define HAVE_SDOT4 0
#endif

__device__ __forceinline__ float sigm(float x){ return 1.f/(1.f+__expf(-x)); }
__device__ __forceinline__ float tanh_(float x){ return 1.f - 2.f/(__expf(2.f*x)+1.f); }

__device__ __forceinline__ int sdot4_acc(unsigned int a, unsigned int b, int acc){
#if HAVE_SDOT4
  return __builtin_amdgcn_sdot4((int)a, (int)b, acc, false);
#else
  int s = acc;
  #pragma unroll
  for (int e=0;e<4;++e){
    int av = (int)(signed char)((a >> (8*e)) & 0xff);
    int bv = (int)(signed char)((b >> (8*e)) & 0xff);
    s += av*bv;
  }
  return s;
#endif
}
__device__ __forceinline__ unsigned short f2bf(float x){
  __hip_bfloat16 b = __float2bfloat16(x);
  return __builtin_bit_cast(unsigned short, b);
}

// bias4[g] = b_ih[g] + b_hh[g] + sum_f conv_b[f]*w_ih[g][f]
__global__ __launch_bounds__(256) void k_bias(const float* __restrict__ conv_b,
                                              const float* __restrict__ w_ih,
                                              const float* __restrict__ b_ih,
                                              const float* __restrict__ b_hh,
                                              float* __restrict__ bias4){
  int g = blockIdx.x*256 + threadIdx.x;
  const float* row = w_ih + (size_t)g*NF;
  float s = b_ih[g] + b_hh[g];
  for (int f=0; f<NF; f+=4){
    float4 w4 = *(const float4*)(row+f);
    float4 c4 = *(const float4*)(conv_b+f);
    s += w4.x*c4.x + w4.y*c4.y + w4.z*c4.z + w4.w*c4.w;
  }
  bias4[g] = s;
}

// per-row quantization scales for w_hh
__global__ __launch_bounds__(256) void k_scale(const float* __restrict__ w_hh,
                                               float* __restrict__ stepv,
                                               float* __restrict__ sws){
  int row = blockIdx.x*256 + threadIdx.x;
  const float* p = w_hh + (size_t)row*NH;
  float m = 0.f;
  for (int c=0;c<NH;c+=4){
    float4 v = *(const float4*)(p+c);
    m = fmaxf(m, fmaxf(fmaxf(fabsf(v.x),fabsf(v.y)), fmaxf(fabsf(v.z),fabsf(v.w))));
  }
  float st = fmaxf(m, 1e-20f) / 127.f;
  stepv[row] = st;
  sws[row]   = st / 127.f;
}

// Pack w_hh -> i8 (1024-thread rnn layout). pq6[i][tid], i<16:
// tid=(w*64+l), kq=w>>2, jq=w&3. Comp r: row=jq*256+l*4+r, cols kq*64+i*4+e.
__global__ __launch_bounds__(256) void k_pack6(const float* __restrict__ w_hh,
                                               const float* __restrict__ stepv,
                                               uint4* __restrict__ pq6){
  int gid = blockIdx.x*256 + threadIdx.x;   // 0..16383
  int i = gid >> 10, tid = gid & 1023;
  int w = tid >> 6, l = tid & 63, kq = w >> 2, jq = w & 3;
  unsigned int words[4];
  #pragma unroll
  for (int r=0; r<4; ++r){
    int row = jq*256 + l*4 + r;
    float st = stepv[row];
    unsigned int acc = 0;
    #pragma unroll
    for (int e=0; e<4; ++e){
      int col = kq*64 + i*4 + e;
      int q = __float2int_rn(w_hh[(size_t)row*NH + col] / st);
      q = max(-127, min(127, q));
      acc |= ((unsigned int)(unsigned char)(signed char)q) << (8*e);
    }
    words[r] = acc;
  }
  pq6[(size_t)i*1024 + tid] = make_uint4(words[0],words[1],words[2],words[3]);
}

// CW2T[g][k] = sum_f w_ih[g][f] * conv_w_flat[k][f]   (bf16 [1024][768])
__global__ __launch_bounds__(256) void k_cw2(const float* __restrict__ w_ih,
                                             const float* __restrict__ conv_w,
                                             unsigned short* __restrict__ cw2t){
  __shared__ float al[64][17];
  __shared__ float bl[16][64];
  const int n0  = blockIdx.x*64;
  const int m0  = blockIdx.y*64;
  const int tid = threadIdx.x;
  const int ty  = tid>>4, tx = tid&15;
  const int rr  = tid>>2, kq = (tid&3)<<2;
  float acc[4][4];
  #pragma unroll
  for (int i=0;i<4;++i){ acc[i][0]=0.f; acc[i][1]=0.f; acc[i][2]=0.f; acc[i][3]=0.f; }

  for (int k0=0; k0<256; k0+=16){
    __syncthreads();
    {
      float4 v = *(const float4*)(w_ih + (size_t)(m0+rr)*NF + k0 + kq);
      al[rr][kq+0]=v.x; al[rr][kq+1]=v.y; al[rr][kq+2]=v.z; al[rr][kq+3]=v.w;
      float4 u = *(const float4*)(conv_w + (size_t)(n0+rr)*NF + k0 + kq);
      bl[kq+0][rr]=u.x; bl[kq+1][rr]=u.y; bl[kq+2][rr]=u.z; bl[kq+3][rr]=u.w;
    }
    __syncthreads();
    #pragma unroll
    for (int kk=0; kk<16; ++kk){
      float a0=al[ty*4+0][kk], a1=al[ty*4+1][kk], a2=al[ty*4+2][kk], a3=al[ty*4+3][kk];
      float4 bv = *(const float4*)&bl[kk][tx*4];
      acc[0][0]+=a0*bv.x; acc[0][1]+=a0*bv.y; acc[0][2]+=a0*bv.z; acc[0][3]+=a0*bv.w;
      acc[1][0]+=a1*bv.x; acc[1][1]+=a1*bv.y; acc[1][2]+=a1*bv.z; acc[1][3]+=a1*bv.w;
      acc[2][0]+=a2*bv.x; acc[2][1]+=a2*bv.y; acc[2][2]+=a2*bv.z; acc[2][3]+=a2*bv.w;
      acc[3][0]+=a3*bv.x; acc[3][1]+=a3*bv.y; acc[3][2]+=a3*bv.z; acc[3][3]+=a3*bv.w;
    }
  }
  #pragma unroll
  for (int i=0;i<4;++i){
    size_t r = (size_t)m0 + ty*4 + i;
    unsigned int p0 = (unsigned int)f2bf(acc[i][0]) | ((unsigned int)f2bf(acc[i][1])<<16);
    unsigned int p1 = (unsigned int)f2bf(acc[i][2]) | ((unsigned int)f2bf(acc[i][3])<<16);
    *(uint2*)(cw2t + r*768 + n0 + tx*4) = make_uint2(p0, p1);
  }
}

// Fused chunk kernel: WGs [0,64) run the RNN for chunk c (reading xh_r);
// WGs [64, 64+n_fxg) produce chunk c+1's xh (writing xh_w) on otherwise-idle
// CUs. No cross-WG communication (different buffers). 1024 thr/WG.
// RNN: i8 sdot4; weights LDS i<6 (96 KB) + 10 uint4 regs. fxg: 16 waves,
// per-wave 32x64 MFMA tile (acc[2][4] -> ~75 VGPR, fits the 128 cap).
__global__ __attribute__((amdgpu_flat_work_group_size(1024,1024)))
__attribute__((amdgpu_waves_per_eu(4,4)))
void k_step(const int* __restrict__ ipts, const float* __restrict__ emb,
            const unsigned short* __restrict__ cw2t, const float* __restrict__ bias4,
            const unsigned short* __restrict__ xh_r, unsigned short* __restrict__ xh_w,
            const uint4* __restrict__ pq6, const float* __restrict__ sws,
            const float* __restrict__ h0, const float* __restrict__ c0,
            const int* __restrict__ seqlen,
            const float* __restrict__ lin_w, const float* __restrict__ lin_b,
            float* __restrict__ h_ws, float* __restrict__ c_ws, float* __restrict__ ms_ws,
            float* __restrict__ out,
            int t0r, int tcount, int is_first, int is_last,
            int t0f, int do_rnn, int n_fxg){
  __shared__ __align__(16) char smem[115968];
  const int tid  = threadIdx.x;
  const int nrnn = do_rnn ? 64 : 0;

  if ((int)blockIdx.x < nrnn){
    // ================= RNN path =================
    uint4*        wlds = (uint4*)smem;                        // [6*1024] 96 KB
    float*        part = (float*)(smem + 98304);              // [4*1024] 16 KB
    unsigned int* hq   = (unsigned int*)(smem + 114688);      // [64]
    float*        red  = (float*)(smem + 114944);             // [256]
    const int b  = blockIdx.x;
    const int l  = tid & 63, w = tid >> 6;
    const int kq = w >> 2, jq = w & 3;
    const int rbase = jq*256 + l*4;

    #pragma unroll
    for (int i=0;i<6;++i) wlds[i*1024 + tid] = pq6[(size_t)i*1024 + tid];

    uint4 wreg[10];
    #pragma unroll
    for (int i=6;i<16;++i) wreg[i-6] = pq6[(size_t)i*1024 + tid];
    #pragma unroll
    for (int i=0;i<10;++i)
      asm volatile("" : "+v"(wreg[i].x), "+v"(wreg[i].y), "+v"(wreg[i].z), "+v"(wreg[i].w));

    float swr[4];
    #pragma unroll
    for (int r=0;r<4;++r) swr[r] = sws[rbase + r];

    const int L = seqlen[b];
    float creg = 0.f, msum = 0.f, hlast = 0.f;
    if (tid < 256){
      float hv;
      if (is_first){ hv = h0[(size_t)b*NH + tid]; creg = c0[(size_t)b*NH + tid]; }
      else { hv = h_ws[b*256 + tid]; creg = c_ws[b*256 + tid]; msum = ms_ws[b*256 + tid]; }
      hlast = hv;
      int q = __float2int_rn(hv * 127.f); q = max(-127, min(127, q));
      ((signed char*)hq)[tid] = (signed char)q;
    }
    __syncthreads();

    const unsigned short* xrow = xh_r + (size_t)b*NG + tid;

    for (int tl=0; tl<tcount; ++tl){
      unsigned short xr0=0, xr1=0, xr2=0, xr3=0;
      if (tid < 256){
        const unsigned short* xr = xrow + (size_t)tl*NB*NG;
        xr0 = xr[0]; xr1 = xr[256]; xr2 = xr[512]; xr3 = xr[768];
      }

      // h as 4 vector reads (compile-time indexed thereafter)
      unsigned int hws[16];
      #pragma unroll
      for (int c=0;c<4;++c){
        uint4 t = *(const uint4*)&hq[kq*16 + c*4];
        hws[c*4+0]=t.x; hws[c*4+1]=t.y; hws[c*4+2]=t.z; hws[c*4+3]=t.w;
      }

      int pa[4] = {0,0,0,0};
      #pragma unroll
      for (int i=0;i<16;++i){
        unsigned int hw = hws[i];
        uint4 wv4 = (i < 6) ? wlds[i*1024 + tid] : wreg[i-6];
        pa[0] = sdot4_acc(wv4.x, hw, pa[0]);
        pa[1] = sdot4_acc(wv4.y, hw, pa[1]);
        pa[2] = sdot4_acc(wv4.z, hw, pa[2]);
        pa[3] = sdot4_acc(wv4.w, hw, pa[3]);
      }
      *(float4*)&part[kq*1024 + rbase] = make_float4(
          (float)pa[0]*swr[0], (float)pa[1]*swr[1],
          (float)pa[2]*swr[2], (float)pa[3]*swr[3]);
      __syncthreads();

      if (tid < 256){
        unsigned short xr4[4] = {xr0, xr1, xr2, xr3};
        float a[4];
        #pragma unroll
        for (int g=0; g<4; ++g){
          float s = (float)__builtin_bit_cast(_Float16, xr4[g]);
          int idx = g*256 + tid;
          #pragma unroll
          for (int k=0;k<4;++k) s += part[k*1024 + idx];
          a[g] = s;
        }
        float si = sigm(a[0]), sf = sigm(a[1]), so = sigm(a[3]);
        float tg = tanh_(a[2]);
        creg = sf*creg + si*tg;
        float h2 = so*tanh_(creg);
        if (t0r + tl < L) msum += h2;
        hlast = h2;
        int q2 = __float2int_rn(h2 * 127.f); q2 = max(-127, min(127, q2));
        ((signed char*)hq)[tid] = (signed char)q2;
      }
      __syncthreads();
    }

    if (tid < 256){
      h_ws[b*256 + tid]  = hlast;
      c_ws[b*256 + tid]  = creg;
      ms_ws[b*256 + tid] = msum;
    }

    if (is_last){
      if (tid < 256) red[tid] = (msum / (float)L) * lin_w[tid];
      __syncthreads();
      if (tid < 64){
        float s = red[tid] + red[tid+64] + red[tid+128] + red[tid+192];
        #pragma unroll
        for (int off=32; off>0; off>>=1) s += __shfl_down(s, off);
        if (tid==0) out[b] = sigm(s + lin_b[0]);
      }
    }
  } else {
    // ================= fxg path (produces next chunk's xh) =================
    int fidx = (int)blockIdx.x - nrnn;
    if (fidx >= n_fxg) return;
    unsigned short* A_l  = (unsigned short*)smem;             // [128*72]
    unsigned short* B_l  = (unsigned short*)(smem + 18432);   // [256*72]
    int*            tokl = (int*)(smem + 55296);              // [4*64]
    const int l  = tid & 63, wv = tid >> 6;
    const int m0 = (fidx >> 2) * 128;
    const int n0 = (fidx & 3) * 256;
    const int TL0 = m0 >> 6;

    if (tid < 256){
      int tv = tid >> 6, bb = tid & 63;
      int s = t0f + TL0 + tv;
      tokl[tid] = (s < SLEN) ? ipts[bb*SLEN + s] : 0;
    }

    f32x4 acc[2][4];
    #pragma unroll
    for (int mt=0; mt<2; ++mt)
      #pragma unroll
      for (int nt=0; nt<4; ++nt)
        acc[mt][nt] = (f32x4){0.f,0.f,0.f,0.f};

    const int wm = wv >> 2, wn = wv & 3;   // 4 m-quarters x 4 n-quarters
    const int lr = l & 15, lk = l >> 4;

    for (int ks = 0; ks < 12; ++ks){
      const int w0 = ks >> 2;
      const int e0 = (ks & 3) << 6;
      __syncthreads();
      // stage A: 128 rows x 64 cols bf16, one uint4 per thread
      {
        int row = tid >> 3, off = tid & 7;
        int tok = tokl[((row>>6) + w0)*64 + (row & 63)];
        const float* src = emb + (size_t)tok*NE + e0 + off*8;
        float4 f0 = *(const float4*)src;
        float4 f1 = *(const float4*)(src+4);
        unsigned int p0 = (unsigned int)f2bf(f0.x) | ((unsigned int)f2bf(f0.y)<<16);
        unsigned int p1 = (unsigned int)f2bf(f0.z) | ((unsigned int)f2bf(f0.w)<<16);
        unsigned int p2 = (unsigned int)f2bf(f1.x) | ((unsigned int)f2bf(f1.y)<<16);
        unsigned int p3 = (unsigned int)f2bf(f1.z) | ((unsigned int)f2bf(f1.w)<<16);
        *(uint4*)&A_l[row*72 + off*8] = make_uint4(p0,p1,p2,p3);
      }
      // stage B: 256 rows x 64 cols, two uint4 per thread
      #pragma unroll
      for (int s2 = 0; s2 < 2; ++s2){
        int seg = tid + s2*1024;
        int row = seg >> 3, off = seg & 7;
        uint4 v = *(const uint4*)(cw2t + (size_t)(n0+row)*768 + (ks<<6) + off*8);
        *(uint4*)&B_l[row*72 + off*8] = v;
      }
      __syncthreads();
      #pragma unroll
      for (int kf = 0; kf < 2; ++kf){
        bf16x8 af[2], bfr[4];
        #pragma unroll
        for (int mt=0; mt<2; ++mt)
          af[mt] = *(const bf16x8*)&A_l[(wm*32 + mt*16 + lr)*72 + kf*32 + lk*8];
        #pragma unroll
        for (int nt=0; nt<4; ++nt)
          bfr[nt] = *(const bf16x8*)&B_l[(wn*64 + nt*16 + lr)*72 + kf*32 + lk*8];
        #pragma unroll
        for (int mt=0; mt<2; ++mt)
          #pragma unroll
          for (int nt=0; nt<4; ++nt)
            acc[mt][nt] = __builtin_amdgcn_mfma_f32_16x16x32_bf16(af[mt], bfr[nt], acc[mt][nt], 0,0,0);
      }
    }

    float bia[4];
    #pragma unroll
    for (int nt=0; nt<4; ++nt) bia[nt] = bias4[n0 + wn*64 + nt*16 + lr];
    #pragma unroll
    for (int mt=0; mt<2; ++mt){
      #pragma unroll
      for (int nt=0; nt<4; ++nt){
        #pragma unroll
        for (int r=0; r<4; ++r){
          int row = m0 + wm*32 + mt*16 + lk*4 + r;
          int col = n0 + wn*64 + nt*16 + lr;
          _Float16 hv = (_Float16)(acc[mt][nt][r] + bia[nt]);
          xh_w[(size_t)row*NG + col] = __builtin_bit_cast(unsigned short, hv);
        }
      }
    }
  }
}

extern "C" void kernel_launch(void* const* d_in, const int* in_sizes, int n_in,
                              void* d_out, int out_size, void* d_ws, size_t ws_size,
                              hipStream_t stream){
  const int*   ipts   = (const int*)d_in[0];
  const int*   seqlen = (const int*)d_in[1];
  const float* h0     = (const float*)d_in[2];
  const float* c0     = (const float*)d_in[3];
  const float* emb    = (const float*)d_in[4];
  const float* conv_w = (const float*)d_in[5];
  const float* conv_b = (const float*)d_in[6];
  const float* w_ih   = (const float*)d_in[7];
  const float* w_hh   = (const float*)d_in[8];
  const float* b_ih   = (const float*)d_in[9];
  const float* b_hh   = (const float*)d_in[10];
  const float* lin_w  = (const float*)d_in[11];
  const float* lin_b  = (const float*)d_in[12];
  float* out = (float*)d_out;

  char* ws = (char*)d_ws;
  const size_t XH_B   = (size_t)TC*NB*NG*2;       // 16.78 MB each
  const size_t CW2_B  = (size_t)NG*768*2;         // 1.57 MB
  const size_t PQ_B   = (size_t)16*1024*16;       // 256 KB
  size_t off = 0;
  unsigned short* xhA   = (unsigned short*)(ws + off); off += XH_B;
  unsigned short* xhB   = (unsigned short*)(ws + off); off += XH_B;
  unsigned short* cw2t  = (unsigned short*)(ws + off); off += CW2_B;
  uint4*          pq6   = (uint4*)(ws + off);          off += PQ_B;
  float*          stepv = (float*)(ws + off);          off += 4096;
  float*          sws   = (float*)(ws + off);          off += 4096;
  float*          bias4 = (float*)(ws + off);          off += 4096;
  float*          h_ws  = (float*)(ws + off);          off += 65536;
  float*          c_ws  = (float*)(ws + off);          off += 65536;
  float*          ms_ws = (float*)(ws + off);          off += 65536;

  k_bias <<<dim3(4),      dim3(256), 0, stream>>>(conv_b, w_ih, b_ih, b_hh, bias4);
  k_scale<<<dim3(4),      dim3(256), 0, stream>>>(w_hh, stepv, sws);
  k_pack6<<<dim3(64),     dim3(256), 0, stream>>>(w_hh, stepv, pq6);
  k_cw2  <<<dim3(12, 16), dim3(256), 0, stream>>>(w_ih, conv_w, cw2t);

  unsigned short* bufs[2] = {xhA, xhB};
  const int nchunks = (TLEN + TC - 1) / TC;   // 8
  auto nf_of = [](int tc){ return 4 * ((tc + 1) / 2); };

  // boot: produce chunk 0's xh (fxg-only launch)
  {
    int tc0 = (TLEN < TC) ? TLEN : TC;
    int nf0 = nf_of(tc0);
    k_step<<<dim3(nf0), dim3(1024), 0, stream>>>(
        ipts, emb, cw2t, bias4, bufs[0], bufs[0], pq6, sws, h0, c0, seqlen,
        lin_w, lin_b, h_ws, c_ws, ms_ws, out,
        0, 0, 0, 0, /*t0f=*/0, /*do_rnn=*/0, nf0);
  }

  for (int c = 0; c < nchunks; ++c){
    int t0 = c*TC;
    int tcount = (TLEN - t0 < TC) ? (TLEN - t0) : TC;
    int nf = 0, t0f = 0;
    unsigned short* xw = bufs[0];
    if (c + 1 < nchunks){
      int t0n = (c+1)*TC;
      int tcn = (TLEN - t0n < TC) ? (TLEN - t0n) : TC;
      nf  = nf_of(tcn);
      t0f = t0n;
      xw  = bufs[(c+1) & 1];
    }
    k_step<<<dim3(64 + nf), dim3(1024), 0, stream>>>(
        ipts, emb, cw2t, bias4, bufs[c & 1], xw, pq6, sws, h0, c0, seqlen,
        lin_w, lin_b, h_ws, c_ws, ms_ws, out,
        t0, tcount, (c==0), (c==nchunks-1), t0f, /*do_rnn=*/1, nf);
  }
}